// Round 3
// baseline (782.483 us; speedup 1.0000x reference)
//
#include <hip/hip_runtime.h>
#include <hip/hip_bf16.h>
#include <stdint.h>

// ---------------------------------------------------------------------------
// SUB_NO=20, T_NO=201, T_DATA=100000, E_NO=800, I_NO=200.
// Input/output dtype (f32 vs bf16) detected ON DEVICE from S_e bit patterns:
// bf16 values in [0,1) never set bit15 of a packed u32; f32 mantissas do
// (p=0.5/word, 64 words scanned -> P(miss)=2^-64). All kernels branch on it.
// Tree recursion is per-timestep independent (children 2s+1, 2s+2 > s).
// ---------------------------------------------------------------------------
constexpr int T    = 100000;
constexpr int TNO  = 201;
constexpr int KP   = 204;     // taps zero-padded to multiple of 4
constexpr int NSUB = 20;
constexpr int ENO  = 800;
constexpr int INO  = 200;
constexpr int NCS  = 40;      // 2 channels * 20 subunits

// d_out: [0,T) voltage | filters 40*201 | C_syn_e 20*800 | C_syn_i 20*200
constexpr int OUT_FILT = T;
constexpr int OUT_CSE  = OUT_FILT + NCS * TNO;

// ws byte offsets
constexpr int WS_KFLIP = 0;        // f32 [40][204]
constexpr int WS_OFFE  = 32640;    // int[21]
constexpr int WS_OFFI  = 32768;    // int[21]
constexpr int WS_PERME = 32896;    // int[800]
constexpr int WS_PERMI = 36096;    // int[200]
constexpr int WS_FLAG  = 36896;    // int (1 = f32, 0 = bf16)
constexpr int WS_SYN   = 36928;    // f32 [40][T] (split path only, 16 MB)
constexpr size_t WS_NEEDED_SPLIT = (size_t)WS_SYN + (size_t)NCS * T * 4;

__device__ __forceinline__ float u16f(unsigned short u) {
  return __uint_as_float((unsigned int)u << 16);   // bf16 bits -> f32 (exact)
}
__device__ __forceinline__ float ldany(const void* p, int i, int f32) {
  return f32 ? ((const float*)p)[i] : u16f(((const unsigned short*)p)[i]);
}
__device__ __forceinline__ void stany(void* p, int i, float v, int f32) {
  if (f32) ((float*)p)[i] = v;
  else     ((__hip_bfloat16*)p)[i] = __float2bfloat16(v);
}
// NaN-free tanh: exact +-1 on expf overflow/underflow, fine at bf16 tolerance.
__device__ __forceinline__ float safe_tanh(float x) {
  return 1.f - 2.f / (expf(2.f * x) + 1.f);
}

// ---------------------------------------------------------------------------
// Kernel 0: dtype detector. 1 block x 64 threads.
// ---------------------------------------------------------------------------
__global__ __launch_bounds__(64) void kern_detect(
    const uint32_t* __restrict__ SeW, int* __restrict__ flag)
{
  const uint32_t w = SeW[threadIdx.x];
  const unsigned long long b = __ballot((w & 0x8000u) != 0u);
  if (threadIdx.x == 0) *flag = (b != 0ull) ? 1 : 0;
}

// ---------------------------------------------------------------------------
// Kernel A: alpha kernels (plain + flipped/padded), perm lists, passthrough.
// 40 blocks x 256 threads.
// ---------------------------------------------------------------------------
__global__ __launch_bounds__(256) void kern_setup(
    const void* __restrict__ Wsyn,
    const void* __restrict__ Tau,
    const void* __restrict__ Delta,
    const void* __restrict__ Cse,
    const void* __restrict__ Csi,
    void* __restrict__ out,
    float* __restrict__ kflip,
    int* __restrict__ offE, int* __restrict__ offI,
    int* __restrict__ permE, int* __restrict__ permI,
    const int* __restrict__ flagp)
{
  __shared__ int cnt[NSUB], offsh[NSUB + 1], pos[ENO], asg[ENO];

  const int f32 = *flagp;
  const int tid = threadIdx.x;
  const int cs  = blockIdx.x;      // 0..39
  const int s   = cs % NSUB;
  const int c   = cs / NSUB;       // 0=e, 1=i

  if (tid <= 200) {
    const float tau = (float)tid;
    float v = 0.f;
#pragma unroll
    for (int j = 0; j < 2; ++j) {
      const float W  = ldany(Wsyn , (s * 2 + j) * 2 + c, f32);
      const float Tu = ldany(Tau  , (s * 2 + j) * 2 + c, f32);
      const float De = ldany(Delta, (s * 2 + j) * 2 + c, f32);
      const float td = fmaxf(tau - De, 0.f);
      const float tt = td / expf(Tu);
      v += tt * expf(-tt) * W;
    }
    stany(out, OUT_FILT + cs * TNO + tid, v, f32);
    kflip[cs * KP + (200 - tid)] = v;       // kflip[j] = kern[200-j]
  } else if (tid < KP) {
    kflip[cs * KP + tid] = 0.f;             // zero pad taps 201..203
  }

  // passthrough C_syn_e / C_syn_i
  for (int idx = blockIdx.x * 256 + tid; idx < NSUB * (ENO + INO); idx += 40 * 256) {
    const float v = (idx < NSUB * ENO) ? ldany(Cse, idx, f32)
                                       : ldany(Csi, idx - NSUB * ENO, f32);
    stany(out, OUT_CSE + idx, v, f32);
  }

  if (blockIdx.x == 0) {
    // ---- excitatory ----
    if (tid < NSUB) cnt[tid] = 0;
    __syncthreads();
    for (int e = tid; e < ENO; e += 256) {
      int a = 0;
      for (int ss = 0; ss < NSUB; ++ss)
        if (ldany(Cse, ss * ENO + e, f32) > 0.5f) a = ss;
      asg[e] = a;
      pos[e] = atomicAdd(&cnt[a], 1);
    }
    __syncthreads();
    if (tid == 0) {
      int acc = 0;
      for (int ss = 0; ss < NSUB; ++ss) { offsh[ss] = acc; acc += cnt[ss]; }
      offsh[NSUB] = acc;
    }
    __syncthreads();
    if (tid <= NSUB) offE[tid] = offsh[tid];
    for (int e = tid; e < ENO; e += 256) permE[offsh[asg[e]] + pos[e]] = e;
    __syncthreads();
    // ---- inhibitory ----
    if (tid < NSUB) cnt[tid] = 0;
    __syncthreads();
    for (int e = tid; e < INO; e += 256) {
      int a = 0;
      for (int ss = 0; ss < NSUB; ++ss)
        if (ldany(Csi, ss * INO + e, f32) > 0.5f) a = ss;
      asg[e] = a;
      pos[e] = atomicAdd(&cnt[a], 1);
    }
    __syncthreads();
    if (tid == 0) {
      int acc = 0;
      for (int ss = 0; ss < NSUB; ++ss) { offsh[ss] = acc; acc += cnt[ss]; }
      offsh[NSUB] = acc;
    }
    __syncthreads();
    if (tid <= NSUB) offI[tid] = offsh[tid];
    for (int e = tid; e < INO; e += 256) permI[offsh[asg[e]] + pos[e]] = e;
  }
}

// ---------------------------------------------------------------------------
// Split-path kernel B: segmented aggregation, 16 time rows/block, grid 6250.
// LDS strides odd (801/401/201/101 u32) -> conflict-free gathers.
// ---------------------------------------------------------------------------
__global__ __launch_bounds__(256) void kern_agg(
    const void* __restrict__ Se,
    const void* __restrict__ Si,
    const int* __restrict__ offE, const int* __restrict__ offI,
    const int* __restrict__ permE, const int* __restrict__ permI,
    float* __restrict__ syn,
    const int* __restrict__ flagp)
{
  __shared__ alignas(16) uint32_t lds[16 * 801];       // 51264 B (both dtypes)
  __shared__ int sOffE[NSUB + 1], sOffI[NSUB + 1];
  __shared__ int sPermE[ENO], sPermI[INO];

  const int f32 = *flagp;
  const int tid = threadIdx.x;
  const int t0  = blockIdx.x * 16;

  for (int i = tid; i < ENO; i += 256) sPermE[i] = permE[i];
  for (int i = tid; i < INO; i += 256) sPermI[i] = permI[i];
  if (tid <= NSUB) { sOffE[tid] = offE[tid]; sOffI[tid] = offI[tid]; }

  // ---- e-phase staging
  if (f32) {
    const uint32_t* g = (const uint32_t*)Se + (size_t)t0 * 800;
    for (int f = tid; f < 16 * 800; f += 256) {
      const int r = f / 800;
      lds[r * 801 + (f - r * 800)] = g[f];
    }
  } else {
    const uint32_t* g = (const uint32_t*)Se + (size_t)t0 * 400;
    for (int f = tid; f < 16 * 400; f += 256) {
      const int r = f / 400;
      lds[r * 401 + (f - r * 400)] = g[f];
    }
  }
  __syncthreads();
  for (int task = tid; task < NSUB * 16; task += 256) {
    const int ss = task >> 4, r = task & 15;
    float v = 0.f;
    const int b0 = sOffE[ss], b1 = sOffE[ss + 1];
    if (f32) {
      const float* row = (const float*)lds + r * 801;
      for (int k = b0; k < b1; ++k) v += row[sPermE[k]];
    } else {
      const unsigned short* row = (const unsigned short*)lds + r * 802;
      for (int k = b0; k < b1; ++k) v += u16f(row[sPermE[k]]);
    }
    syn[(size_t)ss * T + t0 + r] = v;
  }
  __syncthreads();
  // ---- i-phase staging
  if (f32) {
    const uint32_t* g = (const uint32_t*)Si + (size_t)t0 * 200;
    for (int f = tid; f < 16 * 200; f += 256) {
      const int r = f / 200;
      lds[r * 201 + (f - r * 200)] = g[f];
    }
  } else {
    const uint32_t* g = (const uint32_t*)Si + (size_t)t0 * 100;
    for (int f = tid; f < 16 * 100; f += 256) {
      const int r = f / 100;
      lds[r * 101 + (f - r * 100)] = g[f];
    }
  }
  __syncthreads();
  for (int task = tid; task < NSUB * 16; task += 256) {
    const int ss = task >> 4, r = task & 15;
    float v = 0.f;
    const int b0 = sOffI[ss], b1 = sOffI[ss + 1];
    if (f32) {
      const float* row = (const float*)lds + r * 201;
      for (int k = b0; k < b1; ++k) v += row[sPermI[k]];
    } else {
      const unsigned short* row = (const unsigned short*)lds + r * 202;
      for (int k = b0; k < b1; ++k) v += u16f(row[sPermI[k]]);
    }
    syn[(size_t)(NSUB + ss) * T + t0 + r] = v;
  }
}

// ---------------------------------------------------------------------------
// Conv + tree core: sybuf holds [40][272] f32 syn with 200-left-halo.
// Conv results written back in place (cols 0..63); tree reads them.
// ---------------------------------------------------------------------------
constexpr int TT  = 64;
constexpr int SBS = 272;

__device__ __forceinline__ void conv_tree_core(
    float* sybuf, const float* __restrict__ kflip,
    const void* __restrict__ Wsub,
    const void* __restrict__ ThetaP,
    const void* __restrict__ Vo,
    void* __restrict__ out, int t0, int tid, int f32)
{
  // conv: 640 threads = 40 cs * 16 groups of 4 rows
  const int cs = tid >> 4;
  const int r0 = (tid & 15) << 2;
  const float*  xb = &sybuf[cs * SBS + r0];
  const float4* kf = (const float4*)(kflip + cs * KP);
  float4 cur = *(const float4*)xb;
  float a0 = 0.f, a1 = 0.f, a2 = 0.f, a3 = 0.f;
  for (int jb = 0; jb < KP; jb += 4) {
    const float4 nxt = *(const float4*)(xb + jb + 4);
    const float4 k   = kf[jb >> 2];
    a0 = fmaf(k.x, cur.x, a0); a1 = fmaf(k.x, cur.y, a1);
    a2 = fmaf(k.x, cur.z, a2); a3 = fmaf(k.x, cur.w, a3);
    a0 = fmaf(k.y, cur.y, a0); a1 = fmaf(k.y, cur.z, a1);
    a2 = fmaf(k.y, cur.w, a2); a3 = fmaf(k.y, nxt.x, a3);
    a0 = fmaf(k.z, cur.z, a0); a1 = fmaf(k.z, cur.w, a1);
    a2 = fmaf(k.z, nxt.x, a2); a3 = fmaf(k.z, nxt.y, a3);
    a0 = fmaf(k.w, cur.w, a0); a1 = fmaf(k.w, nxt.x, a1);
    a2 = fmaf(k.w, nxt.y, a2); a3 = fmaf(k.w, nxt.z, a3);
    cur = nxt;
  }
  __syncthreads();   // all conv reads of sybuf done
  sybuf[cs * SBS + r0 + 0] = a0;
  sybuf[cs * SBS + r0 + 1] = a1;
  sybuf[cs * SBS + r0 + 2] = a2;
  sybuf[cs * SBS + r0 + 3] = a3;
  __syncthreads();

  if (tid < TT) {
    const int t = t0 + tid;
    if (t < T) {
      float wexp[NSUB];
#pragma unroll
      for (int ss = 0; ss < NSUB; ++ss) wexp[ss] = expf(ldany(Wsub, ss, f32));
      float so[NSUB];
#pragma unroll
      for (int ss = NSUB - 1; ss >= 0; --ss) {
        float x = sybuf[ss * SBS + tid] + sybuf[(NSUB + ss) * SBS + tid]
                + ldany(ThetaP, ss, f32);
        if (2 * ss + 1 < NSUB) x += wexp[2 * ss + 1] * so[2 * ss + 1];
        if (2 * ss + 2 < NSUB) x += wexp[2 * ss + 2] * so[2 * ss + 2];
        so[ss] = safe_tanh(x);
      }
      stany(out, t, so[0] * wexp[0] + ldany(Vo, 0, f32), f32);
    }
  }
}

// ---------------------------------------------------------------------------
// Split-path kernel C: stage syn tile from global, then conv+tree.
// ---------------------------------------------------------------------------
__global__ __launch_bounds__(640) void kern_conv_tree(
    const float* __restrict__ kflip,
    const float* __restrict__ syn,
    const void* __restrict__ Wsub,
    const void* __restrict__ ThetaP,
    const void* __restrict__ Vo,
    void* __restrict__ out,
    const int* __restrict__ flagp)
{
  __shared__ alignas(16) float sybuf[NCS * SBS];   // 43520 B
  const int f32 = *flagp;
  const int tid = threadIdx.x;
  const int t0  = blockIdx.x * TT;

  for (int idx = tid; idx < NCS * (TT + KP); idx += 640) {
    const int cs = idx / (TT + KP);
    const int i  = idx - cs * (TT + KP);
    const int g  = t0 - 200 + i;
    float v = 0.f;
    if (g >= 0 && g < T) v = syn[(size_t)cs * T + g];
    sybuf[cs * SBS + i] = v;
  }
  __syncthreads();
  conv_tree_core(sybuf, kflip, Wsub, ThetaP, Vo, out, t0, tid, f32);
}

// ---------------------------------------------------------------------------
// Fused fallback (small ws): per-block aggregation of its own 268-row halo.
// bf16: 34 chunks x 8 rows (stride 501 u32); f32: 68 chunks x 4 rows
// (stride 1001 u32). stage[4008] covers both.
// ---------------------------------------------------------------------------
__global__ __launch_bounds__(640) void kern_fused(
    const void* __restrict__ Se,
    const void* __restrict__ Si,
    const float* __restrict__ kflip,
    const int* __restrict__ offE, const int* __restrict__ offI,
    const int* __restrict__ permE, const int* __restrict__ permI,
    const void* __restrict__ Wsub,
    const void* __restrict__ ThetaP,
    const void* __restrict__ Vo,
    void* __restrict__ out,
    const int* __restrict__ flagp)
{
  __shared__ alignas(16) float    sybuf[NCS * SBS];   // 43520 B
  __shared__ alignas(16) uint32_t stage[4008];        // 16032 B
  __shared__ int sOffE[NSUB + 1], sOffI[NSUB + 1];
  __shared__ int sPermE[ENO], sPermI[INO];

  const int f32 = *flagp;
  const int tid = threadIdx.x;
  const int t0  = blockIdx.x * TT;

  for (int i = tid; i < ENO; i += 640) sPermE[i] = permE[i];
  for (int i = tid; i < INO; i += 640) sPermI[i] = permI[i];
  if (tid <= NSUB) { sOffE[tid] = offE[tid]; sOffI[tid] = offI[tid]; }

  if (!f32) {
    const uint32_t* SeU = (const uint32_t*)Se;
    const uint32_t* SiU = (const uint32_t*)Si;
    for (int c = 0; c < 34; ++c) {          // 34 x 8 rows cover [0,272)
      const int g0 = t0 - 200 + c * 8;
      for (int idx = tid; idx < 8 * 500; idx += 640) {
        const int r = idx / 500;
        const int w = idx - r * 500;
        const int g = g0 + r;
        uint32_t v = 0u;
        if (g >= 0 && g < T)
          v = (w < 400) ? SeU[(size_t)g * 400 + w] : SiU[(size_t)g * 100 + (w - 400)];
        stage[r * 501 + w] = v;
      }
      __syncthreads();
      if (tid < 320) {
        const int isI = tid >= 160;
        const int t2  = isI ? tid - 160 : tid;
        const int ss  = t2 >> 3, r = t2 & 7;
        const int i   = c * 8 + r;
        const unsigned short* row = (const unsigned short*)(stage + r * 501);
        float v = 0.f;
        if (!isI) {
          for (int k = sOffE[ss]; k < sOffE[ss + 1]; ++k) v += u16f(row[sPermE[k]]);
          sybuf[ss * SBS + i] = v;
        } else {
          row += 800;
          for (int k = sOffI[ss]; k < sOffI[ss + 1]; ++k) v += u16f(row[sPermI[k]]);
          sybuf[(NSUB + ss) * SBS + i] = v;
        }
      }
      __syncthreads();
    }
  } else {
    const uint32_t* SeU = (const uint32_t*)Se;
    const uint32_t* SiU = (const uint32_t*)Si;
    for (int c = 0; c < 68; ++c) {          // 68 x 4 rows cover [0,272)
      const int g0 = t0 - 200 + c * 4;
      for (int idx = tid; idx < 4 * 1000; idx += 640) {
        const int r = idx / 1000;
        const int w = idx - r * 1000;
        const int g = g0 + r;
        uint32_t v = 0u;
        if (g >= 0 && g < T)
          v = (w < 800) ? SeU[(size_t)g * 800 + w] : SiU[(size_t)g * 200 + (w - 800)];
        stage[r * 1001 + w] = v;
      }
      __syncthreads();
      if (tid < 160) {
        const int isI = tid >= 80;
        const int t2  = isI ? tid - 80 : tid;
        const int ss  = t2 >> 2, r = t2 & 3;
        const int i   = c * 4 + r;
        const float* row = (const float*)(stage + r * 1001);
        float v = 0.f;
        if (!isI) {
          for (int k = sOffE[ss]; k < sOffE[ss + 1]; ++k) v += row[sPermE[k]];
          sybuf[ss * SBS + i] = v;
        } else {
          row += 800;
          for (int k = sOffI[ss]; k < sOffI[ss + 1]; ++k) v += row[sPermI[k]];
          sybuf[(NSUB + ss) * SBS + i] = v;
        }
      }
      __syncthreads();
    }
  }
  conv_tree_core(sybuf, kflip, Wsub, ThetaP, Vo, out, t0, tid, f32);
}

// ---------------------------------------------------------------------------
extern "C" void kernel_launch(void* const* d_in, const int* in_sizes, int n_in,
                              void* d_out, int out_size, void* d_ws, size_t ws_size,
                              hipStream_t stream)
{
  const void* Se    = d_in[0];
  const void* Si    = d_in[1];
  const void* Cse   = d_in[2];
  const void* Csi   = d_in[3];
  // d_in[4] = C_den (binary-tree topology, hardcoded)
  const void* Wsyn  = d_in[5];
  const void* Tau   = d_in[6];
  const void* Delta = d_in[7];
  const void* Wsub  = d_in[8];
  const void* Theta = d_in[9];
  const void* Vo    = d_in[10];

  char* ws = (char*)d_ws;
  float* kflip = (float*)(ws + WS_KFLIP);
  int*   offE  = (int*)(ws + WS_OFFE);
  int*   offI  = (int*)(ws + WS_OFFI);
  int*   permE = (int*)(ws + WS_PERME);
  int*   permI = (int*)(ws + WS_PERMI);
  int*   flag  = (int*)(ws + WS_FLAG);
  float* syn   = (float*)(ws + WS_SYN);

  kern_detect<<<dim3(1), dim3(64), 0, stream>>>((const uint32_t*)Se, flag);
  kern_setup<<<dim3(NCS), dim3(256), 0, stream>>>(
      Wsyn, Tau, Delta, Cse, Csi, d_out, kflip, offE, offI, permE, permI, flag);

  if (ws_size >= WS_NEEDED_SPLIT) {
    kern_agg<<<dim3(T / 16), dim3(256), 0, stream>>>(
        Se, Si, offE, offI, permE, permI, syn, flag);
    kern_conv_tree<<<dim3((T + TT - 1) / TT), dim3(640), 0, stream>>>(
        kflip, syn, Wsub, Theta, Vo, d_out, flag);
  } else {
    kern_fused<<<dim3((T + TT - 1) / TT), dim3(640), 0, stream>>>(
        Se, Si, kflip, offE, offI, permE, permI, Wsub, Theta, Vo, d_out, flag);
  }
}

// Round 4
// 633.169 us; speedup vs baseline: 1.2358x; 1.2358x over previous
//
#include <hip/hip_runtime.h>
#include <hip/hip_bf16.h>
#include <stdint.h>

// ---------------------------------------------------------------------------
// SUB_NO=20, T_NO=201, T_DATA=100000, E_NO=800, I_NO=200.
// Input/output dtype (f32 vs bf16) detected ON DEVICE from S_e bit patterns
// (R3 bench: inputs are f32 — absmax 1.2e-7). f32 path is the optimized one.
// Tree recursion is per-timestep independent (children 2s+1, 2s+2 > s).
// ---------------------------------------------------------------------------
constexpr int T    = 100000;
constexpr int TNO  = 201;
constexpr int KP   = 204;     // taps zero-padded to multiple of 4
constexpr int NSUB = 20;
constexpr int ENO  = 800;
constexpr int INO  = 200;
constexpr int NCS  = 40;      // 2 channels * 20 subunits

// d_out: [0,T) voltage | filters 40*201 | C_syn_e 20*800 | C_syn_i 20*200
constexpr int OUT_FILT = T;
constexpr int OUT_CSE  = OUT_FILT + NCS * TNO;

// ws byte offsets
constexpr int WS_KFLIP = 0;        // f32 [40][204]
constexpr int WS_OFFE  = 32640;    // int[21]
constexpr int WS_OFFI  = 32768;    // int[21]
constexpr int WS_PERME = 32896;    // int[800]
constexpr int WS_PERMI = 36096;    // int[200]
constexpr int WS_FLAG  = 36896;    // int (1 = f32, 0 = bf16)
constexpr int WS_SYN   = 36928;    // f32 [40][T] (split path only, 16 MB)
constexpr size_t WS_NEEDED_SPLIT = (size_t)WS_SYN + (size_t)NCS * T * 4;

__device__ __forceinline__ float u16f(unsigned short u) {
  return __uint_as_float((unsigned int)u << 16);   // bf16 bits -> f32 (exact)
}
__device__ __forceinline__ float ldany(const void* p, int i, int f32) {
  return f32 ? ((const float*)p)[i] : u16f(((const unsigned short*)p)[i]);
}
__device__ __forceinline__ void stany(void* p, int i, float v, int f32) {
  if (f32) ((float*)p)[i] = v;
  else     ((__hip_bfloat16*)p)[i] = __float2bfloat16(v);
}
// NaN-free tanh: exact +-1 on expf overflow/underflow.
__device__ __forceinline__ float safe_tanh(float x) {
  return 1.f - 2.f / (expf(2.f * x) + 1.f);
}

// ---------------------------------------------------------------------------
// Kernel 0: dtype detector. 1 block x 64 threads.
// ---------------------------------------------------------------------------
__global__ __launch_bounds__(64) void kern_detect(
    const uint32_t* __restrict__ SeW, int* __restrict__ flag)
{
  const uint32_t w = SeW[threadIdx.x];
  const unsigned long long b = __ballot((w & 0x8000u) != 0u);
  if (threadIdx.x == 0) *flag = (b != 0ull) ? 1 : 0;
}

// ---------------------------------------------------------------------------
// Kernel A: alpha kernels (plain + flipped/padded), perm lists, passthrough.
// 40 blocks x 256 threads.
// ---------------------------------------------------------------------------
__global__ __launch_bounds__(256) void kern_setup(
    const void* __restrict__ Wsyn,
    const void* __restrict__ Tau,
    const void* __restrict__ Delta,
    const void* __restrict__ Cse,
    const void* __restrict__ Csi,
    void* __restrict__ out,
    float* __restrict__ kflip,
    int* __restrict__ offE, int* __restrict__ offI,
    int* __restrict__ permE, int* __restrict__ permI,
    const int* __restrict__ flagp)
{
  __shared__ int cnt[NSUB], offsh[NSUB + 1], pos[ENO], asg[ENO];

  const int f32 = *flagp;
  const int tid = threadIdx.x;
  const int cs  = blockIdx.x;      // 0..39
  const int s   = cs % NSUB;
  const int c   = cs / NSUB;       // 0=e, 1=i

  if (tid <= 200) {
    const float tau = (float)tid;
    float v = 0.f;
#pragma unroll
    for (int j = 0; j < 2; ++j) {
      const float W  = ldany(Wsyn , (s * 2 + j) * 2 + c, f32);
      const float Tu = ldany(Tau  , (s * 2 + j) * 2 + c, f32);
      const float De = ldany(Delta, (s * 2 + j) * 2 + c, f32);
      const float td = fmaxf(tau - De, 0.f);
      const float tt = td / expf(Tu);
      v += tt * expf(-tt) * W;
    }
    stany(out, OUT_FILT + cs * TNO + tid, v, f32);
    kflip[cs * KP + (200 - tid)] = v;       // kflip[j] = kern[200-j]
  } else if (tid < KP) {
    kflip[cs * KP + tid] = 0.f;             // zero pad taps 201..203
  }

  // passthrough C_syn_e / C_syn_i
  for (int idx = blockIdx.x * 256 + tid; idx < NSUB * (ENO + INO); idx += 40 * 256) {
    const float v = (idx < NSUB * ENO) ? ldany(Cse, idx, f32)
                                       : ldany(Csi, idx - NSUB * ENO, f32);
    stany(out, OUT_CSE + idx, v, f32);
  }

  if (blockIdx.x == 0) {
    // ---- excitatory ----
    if (tid < NSUB) cnt[tid] = 0;
    __syncthreads();
    for (int e = tid; e < ENO; e += 256) {
      int a = 0;
      for (int ss = 0; ss < NSUB; ++ss)
        if (ldany(Cse, ss * ENO + e, f32) > 0.5f) a = ss;
      asg[e] = a;
      pos[e] = atomicAdd(&cnt[a], 1);
    }
    __syncthreads();
    if (tid == 0) {
      int acc = 0;
      for (int ss = 0; ss < NSUB; ++ss) { offsh[ss] = acc; acc += cnt[ss]; }
      offsh[NSUB] = acc;
    }
    __syncthreads();
    if (tid <= NSUB) offE[tid] = offsh[tid];
    for (int e = tid; e < ENO; e += 256) permE[offsh[asg[e]] + pos[e]] = e;
    __syncthreads();
    // ---- inhibitory ----
    if (tid < NSUB) cnt[tid] = 0;
    __syncthreads();
    for (int e = tid; e < INO; e += 256) {
      int a = 0;
      for (int ss = 0; ss < NSUB; ++ss)
        if (ldany(Csi, ss * INO + e, f32) > 0.5f) a = ss;
      asg[e] = a;
      pos[e] = atomicAdd(&cnt[a], 1);
    }
    __syncthreads();
    if (tid == 0) {
      int acc = 0;
      for (int ss = 0; ss < NSUB; ++ss) { offsh[ss] = acc; acc += cnt[ss]; }
      offsh[NSUB] = acc;
    }
    __syncthreads();
    if (tid <= NSUB) offI[tid] = offsh[tid];
    for (int e = tid; e < INO; e += 256) permI[offsh[asg[e]] + pos[e]] = e;
  }
}

// ---------------------------------------------------------------------------
// Kernel B (v2): segmented aggregation, 8 time rows/block, grid 12500.
// f32: float4 staging (e 1600 + i 400 float4, 7 unrolled independent
// global_load_dwordx4/thread -> deep VMEM pipelining), LDS row stride 1004
// words (16B-aligned b128 writes; gather bank = (12r+p)&31, 8 distinct banks
// across r-lanes -> <=2-way, free). ~36 KB LDS -> 4 blocks/CU (16 waves/CU).
// ---------------------------------------------------------------------------
constexpr int AR   = 8;       // rows per block
constexpr int FSTR = 1004;    // f32 LDS row stride (words): e 0..799, i 800..999
constexpr int BSTR = 504;     // bf16 LDS row stride (words): e 0..399, i 400..499

__global__ __launch_bounds__(256) void kern_agg(
    const void* __restrict__ Se,
    const void* __restrict__ Si,
    const int* __restrict__ offE, const int* __restrict__ offI,
    const int* __restrict__ permE, const int* __restrict__ permI,
    float* __restrict__ syn,
    const int* __restrict__ flagp)
{
  __shared__ alignas(16) uint32_t lds[AR * FSTR];      // 32128 B
  __shared__ int sOffE[NSUB + 1], sOffI[NSUB + 1];
  __shared__ int sPermE[ENO], sPermI[INO];

  const int f32 = *flagp;
  const int tid = threadIdx.x;
  const int t0  = blockIdx.x * AR;

  for (int i = tid; i < ENO; i += 256) sPermE[i] = permE[i];
  for (int i = tid; i < INO; i += 256) sPermI[i] = permI[i];
  if (tid <= NSUB) { sOffE[tid] = offE[tid]; sOffI[tid] = offI[tid]; }

  if (f32) {
    // ---- staging: 2000 float4 (e: idx<1600, i: idx>=1600), both contiguous
    const float4* gE4 = (const float4*)Se + (size_t)t0 * 200;
    const float4* gI4 = (const float4*)Si + (size_t)t0 * 50;
#pragma unroll
    for (int u = 0; u < 7; ++u) {
      const int idx = tid + u * 256;     // < 1792, always valid
      float4 v; int w;
      if (idx < 1600) { v = gE4[idx]; const int r = idx / 200;
                        w = r * FSTR + (idx - r * 200) * 4; }
      else            { const int j = idx - 1600; v = gI4[j]; const int r = j / 50;
                        w = r * FSTR + 800 + (j - r * 50) * 4; }
      *(float4*)&lds[w] = v;
    }
    {
      const int idx = tid + 1792;
      if (idx < 2000) {
        const int j = idx - 1600;
        const int r = j / 50;
        *(float4*)&lds[r * FSTR + 800 + (j - r * 50) * 4] = gI4[j];
      }
    }
  } else {
    // ---- bf16 staging (unused when inputs are f32): 4000 u32 words
    const uint32_t* gE = (const uint32_t*)Se + (size_t)t0 * 400;
    const uint32_t* gI = (const uint32_t*)Si + (size_t)t0 * 100;
    for (int idx = tid; idx < AR * 500; idx += 256) {
      const int r = idx / 500;
      const int w = idx - r * 500;
      lds[r * BSTR + w] = (w < 400) ? gE[r * 400 + w] : gI[r * 100 + (w - 400)];
    }
  }
  __syncthreads();

  // ---- gather: 320 tasks = 40 cs * 8 rows
  for (int task = tid; task < NCS * AR; task += 256) {
    const int cs = task >> 3, r = task & 7;
    float v = 0.f;
    if (f32) {
      const float* row = (const float*)lds + r * FSTR;
      if (cs < NSUB) {
        const int b0 = sOffE[cs], b1 = sOffE[cs + 1];
#pragma unroll 4
        for (int k = b0; k < b1; ++k) v += row[sPermE[k]];
      } else {
        const int ss = cs - NSUB;
        const int b0 = sOffI[ss], b1 = sOffI[ss + 1];
#pragma unroll 4
        for (int k = b0; k < b1; ++k) v += row[800 + sPermI[k]];
      }
    } else {
      const unsigned short* row = (const unsigned short*)lds + r * (BSTR * 2);
      if (cs < NSUB) {
        const int b0 = sOffE[cs], b1 = sOffE[cs + 1];
        for (int k = b0; k < b1; ++k) v += u16f(row[sPermE[k]]);
      } else {
        const int ss = cs - NSUB;
        const int b0 = sOffI[ss], b1 = sOffI[ss + 1];
        for (int k = b0; k < b1; ++k) v += u16f(row[800 + sPermI[k]]);
      }
    }
    syn[(size_t)cs * T + t0 + r] = v;
  }
}

// ---------------------------------------------------------------------------
// Conv + tree core: sybuf holds [40][272] f32 syn with 200-left-halo.
// Conv results written back in place (cols 0..63); tree reads them.
// ---------------------------------------------------------------------------
constexpr int TT  = 64;
constexpr int SBS = 272;

__device__ __forceinline__ void conv_tree_core(
    float* sybuf, const float* __restrict__ kflip,
    const void* __restrict__ Wsub,
    const void* __restrict__ ThetaP,
    const void* __restrict__ Vo,
    void* __restrict__ out, int t0, int tid, int f32)
{
  // conv: 640 threads = 40 cs * 16 groups of 4 rows
  const int cs = tid >> 4;
  const int r0 = (tid & 15) << 2;
  const float*  xb = &sybuf[cs * SBS + r0];
  const float4* kf = (const float4*)(kflip + cs * KP);
  float4 cur = *(const float4*)xb;
  float a0 = 0.f, a1 = 0.f, a2 = 0.f, a3 = 0.f;
  for (int jb = 0; jb < KP; jb += 4) {
    const float4 nxt = *(const float4*)(xb + jb + 4);
    const float4 k   = kf[jb >> 2];
    a0 = fmaf(k.x, cur.x, a0); a1 = fmaf(k.x, cur.y, a1);
    a2 = fmaf(k.x, cur.z, a2); a3 = fmaf(k.x, cur.w, a3);
    a0 = fmaf(k.y, cur.y, a0); a1 = fmaf(k.y, cur.z, a1);
    a2 = fmaf(k.y, cur.w, a2); a3 = fmaf(k.y, nxt.x, a3);
    a0 = fmaf(k.z, cur.z, a0); a1 = fmaf(k.z, cur.w, a1);
    a2 = fmaf(k.z, nxt.x, a2); a3 = fmaf(k.z, nxt.y, a3);
    a0 = fmaf(k.w, cur.w, a0); a1 = fmaf(k.w, nxt.x, a1);
    a2 = fmaf(k.w, nxt.y, a2); a3 = fmaf(k.w, nxt.z, a3);
    cur = nxt;
  }
  __syncthreads();   // all conv reads of sybuf done
  sybuf[cs * SBS + r0 + 0] = a0;
  sybuf[cs * SBS + r0 + 1] = a1;
  sybuf[cs * SBS + r0 + 2] = a2;
  sybuf[cs * SBS + r0 + 3] = a3;
  __syncthreads();

  if (tid < TT) {
    const int t = t0 + tid;
    if (t < T) {
      float wexp[NSUB];
#pragma unroll
      for (int ss = 0; ss < NSUB; ++ss) wexp[ss] = expf(ldany(Wsub, ss, f32));
      float so[NSUB];
#pragma unroll
      for (int ss = NSUB - 1; ss >= 0; --ss) {
        float x = sybuf[ss * SBS + tid] + sybuf[(NSUB + ss) * SBS + tid]
                + ldany(ThetaP, ss, f32);
        if (2 * ss + 1 < NSUB) x += wexp[2 * ss + 1] * so[2 * ss + 1];
        if (2 * ss + 2 < NSUB) x += wexp[2 * ss + 2] * so[2 * ss + 2];
        so[ss] = safe_tanh(x);
      }
      stany(out, t, so[0] * wexp[0] + ldany(Vo, 0, f32), f32);
    }
  }
}

// ---------------------------------------------------------------------------
// Split-path kernel C: stage syn tile from global, then conv+tree.
// ---------------------------------------------------------------------------
__global__ __launch_bounds__(640) void kern_conv_tree(
    const float* __restrict__ kflip,
    const float* __restrict__ syn,
    const void* __restrict__ Wsub,
    const void* __restrict__ ThetaP,
    const void* __restrict__ Vo,
    void* __restrict__ out,
    const int* __restrict__ flagp)
{
  __shared__ alignas(16) float sybuf[NCS * SBS];   // 43520 B
  const int f32 = *flagp;
  const int tid = threadIdx.x;
  const int t0  = blockIdx.x * TT;

  for (int idx = tid; idx < NCS * (TT + KP); idx += 640) {
    const int cs = idx / (TT + KP);
    const int i  = idx - cs * (TT + KP);
    const int g  = t0 - 200 + i;
    float v = 0.f;
    if (g >= 0 && g < T) v = syn[(size_t)cs * T + g];
    sybuf[cs * SBS + i] = v;
  }
  __syncthreads();
  conv_tree_core(sybuf, kflip, Wsub, ThetaP, Vo, out, t0, tid, f32);
}

// ---------------------------------------------------------------------------
// Fused fallback (small ws): per-block aggregation of its own 268-row halo.
// ---------------------------------------------------------------------------
__global__ __launch_bounds__(640) void kern_fused(
    const void* __restrict__ Se,
    const void* __restrict__ Si,
    const float* __restrict__ kflip,
    const int* __restrict__ offE, const int* __restrict__ offI,
    const int* __restrict__ permE, const int* __restrict__ permI,
    const void* __restrict__ Wsub,
    const void* __restrict__ ThetaP,
    const void* __restrict__ Vo,
    void* __restrict__ out,
    const int* __restrict__ flagp)
{
  __shared__ alignas(16) float    sybuf[NCS * SBS];   // 43520 B
  __shared__ alignas(16) uint32_t stage[4008];        // 16032 B
  __shared__ int sOffE[NSUB + 1], sOffI[NSUB + 1];
  __shared__ int sPermE[ENO], sPermI[INO];

  const int f32 = *flagp;
  const int tid = threadIdx.x;
  const int t0  = blockIdx.x * TT;

  for (int i = tid; i < ENO; i += 640) sPermE[i] = permE[i];
  for (int i = tid; i < INO; i += 640) sPermI[i] = permI[i];
  if (tid <= NSUB) { sOffE[tid] = offE[tid]; sOffI[tid] = offI[tid]; }

  if (!f32) {
    const uint32_t* SeU = (const uint32_t*)Se;
    const uint32_t* SiU = (const uint32_t*)Si;
    for (int c = 0; c < 34; ++c) {          // 34 x 8 rows cover [0,272)
      const int g0 = t0 - 200 + c * 8;
      for (int idx = tid; idx < 8 * 500; idx += 640) {
        const int r = idx / 500;
        const int w = idx - r * 500;
        const int g = g0 + r;
        uint32_t v = 0u;
        if (g >= 0 && g < T)
          v = (w < 400) ? SeU[(size_t)g * 400 + w] : SiU[(size_t)g * 100 + (w - 400)];
        stage[r * 501 + w] = v;
      }
      __syncthreads();
      if (tid < 320) {
        const int isI = tid >= 160;
        const int t2  = isI ? tid - 160 : tid;
        const int ss  = t2 >> 3, r = t2 & 7;
        const int i   = c * 8 + r;
        const unsigned short* row = (const unsigned short*)(stage + r * 501);
        float v = 0.f;
        if (!isI) {
          for (int k = sOffE[ss]; k < sOffE[ss + 1]; ++k) v += u16f(row[sPermE[k]]);
          sybuf[ss * SBS + i] = v;
        } else {
          row += 800;
          for (int k = sOffI[ss]; k < sOffI[ss + 1]; ++k) v += u16f(row[sPermI[k]]);
          sybuf[(NSUB + ss) * SBS + i] = v;
        }
      }
      __syncthreads();
    }
  } else {
    const uint32_t* SeU = (const uint32_t*)Se;
    const uint32_t* SiU = (const uint32_t*)Si;
    for (int c = 0; c < 68; ++c) {          // 68 x 4 rows cover [0,272)
      const int g0 = t0 - 200 + c * 4;
      for (int idx = tid; idx < 4 * 1000; idx += 640) {
        const int r = idx / 1000;
        const int w = idx - r * 1000;
        const int g = g0 + r;
        uint32_t v = 0u;
        if (g >= 0 && g < T)
          v = (w < 800) ? SeU[(size_t)g * 800 + w] : SiU[(size_t)g * 200 + (w - 800)];
        stage[r * 1001 + w] = v;
      }
      __syncthreads();
      if (tid < 160) {
        const int isI = tid >= 80;
        const int t2  = isI ? tid - 80 : tid;
        const int ss  = t2 >> 2, r = t2 & 3;
        const int i   = c * 4 + r;
        const float* row = (const float*)(stage + r * 1001);
        float v = 0.f;
        if (!isI) {
          for (int k = sOffE[ss]; k < sOffE[ss + 1]; ++k) v += row[sPermE[k]];
          sybuf[ss * SBS + i] = v;
        } else {
          row += 800;
          for (int k = sOffI[ss]; k < sOffI[ss + 1]; ++k) v += row[sPermI[k]];
          sybuf[(NSUB + ss) * SBS + i] = v;
        }
      }
      __syncthreads();
    }
  }
  conv_tree_core(sybuf, kflip, Wsub, ThetaP, Vo, out, t0, tid, f32);
}

// ---------------------------------------------------------------------------
extern "C" void kernel_launch(void* const* d_in, const int* in_sizes, int n_in,
                              void* d_out, int out_size, void* d_ws, size_t ws_size,
                              hipStream_t stream)
{
  const void* Se    = d_in[0];
  const void* Si    = d_in[1];
  const void* Cse   = d_in[2];
  const void* Csi   = d_in[3];
  // d_in[4] = C_den (binary-tree topology, hardcoded)
  const void* Wsyn  = d_in[5];
  const void* Tau   = d_in[6];
  const void* Delta = d_in[7];
  const void* Wsub  = d_in[8];
  const void* Theta = d_in[9];
  const void* Vo    = d_in[10];

  char* ws = (char*)d_ws;
  float* kflip = (float*)(ws + WS_KFLIP);
  int*   offE  = (int*)(ws + WS_OFFE);
  int*   offI  = (int*)(ws + WS_OFFI);
  int*   permE = (int*)(ws + WS_PERME);
  int*   permI = (int*)(ws + WS_PERMI);
  int*   flag  = (int*)(ws + WS_FLAG);
  float* syn   = (float*)(ws + WS_SYN);

  kern_detect<<<dim3(1), dim3(64), 0, stream>>>((const uint32_t*)Se, flag);
  kern_setup<<<dim3(NCS), dim3(256), 0, stream>>>(
      Wsyn, Tau, Delta, Cse, Csi, d_out, kflip, offE, offI, permE, permI, flag);

  if (ws_size >= WS_NEEDED_SPLIT) {
    kern_agg<<<dim3(T / AR), dim3(256), 0, stream>>>(
        Se, Si, offE, offI, permE, permI, syn, flag);
    kern_conv_tree<<<dim3((T + TT - 1) / TT), dim3(640), 0, stream>>>(
        kflip, syn, Wsub, Theta, Vo, d_out, flag);
  } else {
    kern_fused<<<dim3((T + TT - 1) / TT), dim3(640), 0, stream>>>(
        Se, Si, kflip, offE, offI, permE, permI, Wsub, Theta, Vo, d_out, flag);
  }
}